// Round 17
// baseline (314.736 us; speedup 1.0000x reference)
//
#include <hip/hip_runtime.h>
#include <hip/hip_bf16.h>

#define VIS_DIM 2048
#define TXT_DIM 1024
#define HID     1024
#define NB      128          // batch
#define NR      256          // regions
#define M_TOT   (NB*NR)      // 32768

// bf16 workspace layout (fast path):
//   A tiles: 8192 tiles (rowblk 0..255 x kt 0..31), 16KB each, swizzled image
//   B tiles: 256 tiles (colblk 0..7 x kt 0..31) at tile index 8192
//   scores (128KB) + tbuf (512KB) after the tiles
#define N_ATILES 8192
#define N_TILES  8448
#define TILE_B   16384
#define TSTRIDE  (32 * TILE_B)                              // +1 row-tile
#define WS_SCORES_OFF ((size_t)N_TILES * TILE_B)            // 138412032
#define WS_NEED (WS_SCORES_OFF + 131072 + 524288)           // 139067392

typedef __attribute__((ext_vector_type(4))) float  f32x4;
typedef __attribute__((ext_vector_type(8))) short  short8;   // 8 x bf16
typedef __attribute__((ext_vector_type(4))) unsigned short u16x4;

static __device__ __forceinline__ unsigned short f2bf(float f) {
    union { __hip_bfloat16 h; unsigned short u; } c;
    c.h = __float2bfloat16(f);
    return c.u;
}

static __device__ __forceinline__ float bf2f(unsigned short u) {
    union { float f; unsigned u; } c; c.u = ((unsigned)u) << 16; return c.f;
}

static __device__ __forceinline__ float tanh_fast(float x) {
    float xc = fminf(fmaxf(x, -15.f), 15.f);
    float e  = __expf(2.f * xc);
    return (e - 1.f) / (e + 1.f);
}

// ---------------------------------------------------------------------------
// prepass: fp32 -> bf16 tile-blocked, bank-swizzle baked into the layout.
// Tile (128 rows x 64 k) = 16KB; byte(row,k) = row*128 + (((k>>3)^(row&7))<<4)
// + (k&7)*2. Blocks 0..511 also do init (zero scores, tbuf = bt broadcast).
// ---------------------------------------------------------------------------
__global__ __launch_bounds__(256) void prepass(const float* __restrict__ A,
                                               const float* __restrict__ Bv,
                                               unsigned short* __restrict__ w16,
                                               float* __restrict__ scores,
                                               float* __restrict__ tbuf,
                                               const float* __restrict__ bt) {
    const int t   = blockIdx.x;
    const int tid = threadIdx.x;
    if (t < 512) {                       // fused init_ws (131072 elements)
        int i = t * 256 + tid;
        if (i < M_TOT) scores[i] = 0.f;
        tbuf[i] = bt[i & (HID - 1)];
    }
    const int mb  = (t < N_ATILES ? t : t - N_ATILES) >> 5;
    const int kt  = t & 31;
    const float* src = (t < N_ATILES ? A : Bv) + (size_t)mb * 128 * VIS_DIM + kt * 64;
    unsigned short* dst = w16 + (size_t)t * (TILE_B / 2);
    #pragma unroll
    for (int i = 0; i < 4; ++i) {
        int si = i * 256 + tid;          // 0..1023
        int row = si >> 3, slot = si & 7;
        const float* p = src + (size_t)row * VIS_DIM + slot * 8;
        f32x4 lo = *(const f32x4*)p;
        f32x4 hi = *(const f32x4*)(p + 4);
        short8 v;
        v[0] = (short)f2bf(lo.x); v[1] = (short)f2bf(lo.y);
        v[2] = (short)f2bf(lo.z); v[3] = (short)f2bf(lo.w);
        v[4] = (short)f2bf(hi.x); v[5] = (short)f2bf(hi.y);
        v[6] = (short)f2bf(hi.z); v[7] = (short)f2bf(hi.w);
        *(short8*)(dst + row * 64 + ((slot ^ (row & 7)) << 3)) = v;
    }
}

// ---------------------------------------------------------------------------
// init (fallback path only): zero scores, t = bt broadcast
// ---------------------------------------------------------------------------
__global__ void init_ws(float* __restrict__ scores, float* __restrict__ tbuf,
                        const float* __restrict__ bt) {
    int i = blockIdx.x * 256 + threadIdx.x;
    if (i < M_TOT) scores[i] = 0.f;
    tbuf[i] = bt[i & (HID - 1)];
}

// ---------------------------------------------------------------------------
// t = text @ Wt^T (+bt already in tbuf). Split-K fp32 tiled GEMM, atomicAdd.
// ---------------------------------------------------------------------------
__global__ __launch_bounds__(256) void gemm_text(const float* __restrict__ text,
                                                 const float* __restrict__ Wt,
                                                 float* __restrict__ tbuf) {
    __shared__ float As[128][33];
    __shared__ float Bs[32][33];
    const int n0  = blockIdx.x * 32;
    const int k0  = blockIdx.y * 256;
    const int tid = threadIdx.x;
    const int tm  = tid >> 3;
    const int tn  = tid & 7;
    float acc[4][4] = {};
    for (int kt = 0; kt < 8; ++kt) {
        const int k = k0 + kt * 32;
        {   // stage A: 128x32
            int row = tid >> 1, off = (tid & 1) * 16;
            const float* src = text + row * TXT_DIM + k + off;
            #pragma unroll
            for (int j = 0; j < 4; ++j) {
                f32x4 v = *(const f32x4*)(src + j * 4);
                As[row][off + j*4 + 0] = v.x; As[row][off + j*4 + 1] = v.y;
                As[row][off + j*4 + 2] = v.z; As[row][off + j*4 + 3] = v.w;
            }
        }
        {   // stage B: 32x32
            int row = tid >> 3, off = (tid & 7) * 4;
            f32x4 v = *(const f32x4*)(Wt + (size_t)(n0 + row) * TXT_DIM + k + off);
            Bs[row][off + 0] = v.x; Bs[row][off + 1] = v.y;
            Bs[row][off + 2] = v.z; Bs[row][off + 3] = v.w;
        }
        __syncthreads();
        #pragma unroll
        for (int kk = 0; kk < 32; ++kk) {
            float a[4], b[4];
            #pragma unroll
            for (int i = 0; i < 4; ++i) a[i] = As[tm*4 + i][kk];
            #pragma unroll
            for (int j = 0; j < 4; ++j) b[j] = Bs[tn*4 + j][kk];
            #pragma unroll
            for (int i = 0; i < 4; ++i)
                #pragma unroll
                for (int j = 0; j < 4; ++j) acc[i][j] += a[i] * b[j];
        }
        __syncthreads();
    }
    #pragma unroll
    for (int i = 0; i < 4; ++i)
        #pragma unroll
        for (int j = 0; j < 4; ++j)
            atomicAdd(&tbuf[(tm*4 + i) * HID + n0 + tn*4 + j], acc[i][j]);
}

// ---------------------------------------------------------------------------
// gemm_256 R17: 256x256 tile, BK=64, FOUR waves of 128x128 (acc[8][8]).
// Why: at 8x(128x64), LDS stream (2260cy/tile) ~= MFMA (2483cy) but measured
// ~4425 -> serialized, because 92 arch + 128 acc left no registers to
// software-pipeline reads under MFMAs. 128x128 wave tile: 16 frag-reads
// feed 64 MFMAs (LDS stream -> ~1500cy/tile, below MFMA floor) and
// launch_bounds(256,1) gives a 512-VGPR budget (acc 256 + frags 64 + addr
// ~50 = ~370) -> ~140 free regs let the compiler hoist next-phase reads
// under the current MFMA cluster (no sched fences between phases).
// Schedule unchanged from the proven R14/R16 shape: 2 barriers/tile, tile
// t+1 prefetched a full tile early, raw barriers, setprio'd MFMA clusters.
// Staging: wave w owns image tile w (A0,A1,B0,B1) -- 16 linear gload_lds.
// ---------------------------------------------------------------------------
static __device__ __forceinline__ int toff(int row, int kElem) {
    return row * 128 + ((((kElem >> 3) & 7) ^ (row & 7)) << 4);
}

__global__ __launch_bounds__(256, 1) void gemm_256(
        const unsigned short* __restrict__ w16,
        const float* __restrict__ bv,
        const float* __restrict__ wa,
        const float* __restrict__ tbuf,
        float* __restrict__ scores) {
    // per buffer (64KB): A0,A1,B0,B1 tiles at 0,16K,32K,48K; buf1 at +64K
    __shared__ __align__(16) char lds[131072];

    // 512 blocks = 128 mb x 4 nb; XCD-chunked: each XCD owns 16 mb-groups,
    // nb-fastest so the 4 column-siblings of an A-panel are adjacent.
    const int wg   = blockIdx.x;
    const int xcd  = wg & 7;
    const int loc  = wg >> 3;               // 0..63
    const int mb   = xcd * 16 + (loc >> 2); // 0..127
    const int nb   = loc & 3;               // 0..3
    const int brow = mb * 256;
    const int bcol = nb * 256;

    const int tid  = threadIdx.x;           // 256 thr, 4 waves
    const int lane = tid & 63;
    const int wid  = tid >> 6;              // 0..3
    const int wr   = wid >> 1;              // 0..1 (row half: 128 rows)
    const int wc   = wid & 1;               // 0..1 (col half: 128 cols)
    const int l    = lane & 15, g = lane >> 4;

    // staging: wave w owns image tile w of the K-tile: 0,1 = A row-tiles,
    // 2,3 = B col-tiles. 16 x 1KB gload_lds per wave per K-tile.
    const char* wb = (const char*)w16;
    const char* pW = (wid < 2)
        ? wb + (size_t)(2 * mb + wid) * TSTRIDE + lane * 16
        : wb + (size_t)N_ATILES * TILE_B
             + (size_t)(2 * nb + (wid - 2)) * TSTRIDE + lane * 16;
    const int ldsW = wid * 16384;           // wave's tile slot in a buffer

    f32x4 acc[8][8] = {};

    // issue 16 global_load_lds (1KB each) for this wave's tile at byte koff
#define GLOADS(koff, bufbase)                                                  \
    do {                                                                       \
        _Pragma("unroll")                                                      \
        for (int j = 0; j < 16; ++j) {                                         \
            __builtin_amdgcn_global_load_lds(                                  \
                (const __attribute__((address_space(1))) float*)               \
                    (pW + (koff) + j * 1024),                                  \
                (__attribute__((address_space(3))) float*)                     \
                    (lds + (bufbase) + ldsW + j * 1024),                       \
                16, 0, 0);                                                     \
        }                                                                      \
    } while (0)

#define VWAIT0()                                                               \
    do {                                                                       \
        __builtin_amdgcn_sched_barrier(0);                                     \
        asm volatile("s_waitcnt vmcnt(0)" ::: "memory");                       \
        __builtin_amdgcn_sched_barrier(0);                                     \
    } while (0)

#define BARRIER()                                                              \
    do {                                                                       \
        __builtin_amdgcn_sched_barrier(0);                                     \
        asm volatile("s_waitcnt lgkmcnt(0)" ::: "memory");                     \
        __builtin_amdgcn_s_barrier();                                          \
        __builtin_amdgcn_sched_barrier(0);                                     \
    } while (0)

    // one k-slice (32): 16 frag reads then setprio'd 64-MFMA cluster.
    // NO sched fences inside/between phases: free regs (~140) let the
    // compiler hoist the next phase's reads under this cluster.
#define PHASE(bufbase, s)                                                      \
    do {                                                                       \
        const int kE = (s) * 32 + g * 8;                                       \
        const char* pa_ = lds + (bufbase) + wr * 16384;                        \
        const char* pb_ = lds + (bufbase) + 32768 + wc * 16384;                \
        short8 bfr[8], afr[8];                                                 \
        _Pragma("unroll")                                                      \
        for (int n = 0; n < 8; ++n)                                            \
            bfr[n] = *(const short8*)(pb_ + toff(n * 16 + l, kE));             \
        _Pragma("unroll")                                                      \
        for (int m = 0; m < 8; ++m)                                            \
            afr[m] = *(const short8*)(pa_ + toff(m * 16 + l, kE));             \
        __builtin_amdgcn_s_setprio(1);                                         \
        _Pragma("unroll")                                                      \
        for (int m = 0; m < 8; ++m)                                            \
            _Pragma("unroll")                                                  \
            for (int n = 0; n < 8; ++n)                                        \
                acc[m][n] = __builtin_amdgcn_mfma_f32_16x16x32_bf16(           \
                    afr[m], bfr[n], acc[m][n], 0, 0, 0);                       \
        __builtin_amdgcn_s_setprio(0);                                         \
    } while (0)

    // Prologue: tile0 -> buf0 (drained), tile1 -> buf1 (in flight)
    GLOADS((size_t)0, 0);
    VWAIT0();
    GLOADS((size_t)TILE_B, 65536);
    BARRIER();                 // tile0 visible; tile1 flying

    // 16 pair-iterations over 32 K-tiles. Invariant at iter top: buf0 holds
    // tile 2i (synced); tile 2i+1's loads in flight into buf1.
    #pragma unroll 1
    for (int i = 0; i < 16; ++i) {
        const size_t k2 = (size_t)(2 * i + 2) * TILE_B;
        PHASE(0, 0);
        PHASE(0, 1);           // tile 2i computed
        VWAIT0();              // tile 2i+1 landed (hidden under compute)
        BARRIER();             // everyone done reading buf0
        if (i < 15) GLOADS(k2, 0);            // tile 2i+2 -> buf0 (flying)
        PHASE(65536, 0);
        PHASE(65536, 1);       // tile 2i+1 computed
        if (i < 15) {
            VWAIT0();          // tile 2i+2 landed
            BARRIER();         // everyone done reading buf1
            GLOADS(k2 + TILE_B, 65536);       // tile 2i+3 -> buf1 (flying)
        }
    }
#undef GLOADS
#undef VWAIT0
#undef BARRIER
#undef PHASE

    // ---- epilogue: tanh + Wa-dot, reduce over 16 cols/lane-group, atomicAdd
    const int b = mb;                        // block == one batch (256 rows)
    float wa_c[8], bvt_c[8];
    #pragma unroll
    for (int n = 0; n < 8; ++n) {
        int col = bcol + wc * 128 + n * 16 + l;
        wa_c[n]  = wa[col];
        bvt_c[n] = bv[col] + tbuf[b * HID + col];
    }
    #pragma unroll
    for (int m = 0; m < 8; ++m) {
        float p0 = 0.f, p1 = 0.f, p2 = 0.f, p3 = 0.f;
        #pragma unroll
        for (int n = 0; n < 8; ++n) {
            f32x4 v = acc[m][n];
            p0 += wa_c[n] * tanh_fast(v.x + bvt_c[n]);
            p1 += wa_c[n] * tanh_fast(v.y + bvt_c[n]);
            p2 += wa_c[n] * tanh_fast(v.z + bvt_c[n]);
            p3 += wa_c[n] * tanh_fast(v.w + bvt_c[n]);
        }
        #pragma unroll
        for (int d = 1; d < 16; d <<= 1) {
            p0 += __shfl_xor(p0, d); p1 += __shfl_xor(p1, d);
            p2 += __shfl_xor(p2, d); p3 += __shfl_xor(p3, d);
        }
        if ((lane & 15) == 0) {
            int rowg = brow + wr * 128 + m * 16 + g * 4;
            atomicAdd(&scores[rowg + 0], p0);
            atomicAdd(&scores[rowg + 1], p1);
            atomicAdd(&scores[rowg + 2], p2);
            atomicAdd(&scores[rowg + 3], p3);
        }
    }
}

// ---------------------------------------------------------------------------
// attend_bf16: softmax + attended = w . visual, reading the bf16 tile image
// (128 MB, mostly L3-resident after gemm_256) instead of fp32 visual.
// ---------------------------------------------------------------------------
__global__ __launch_bounds__(256) void attend_bf16(
        const unsigned short* __restrict__ w16,
        const float* __restrict__ scores,
        float* __restrict__ out) {
    const int chunk = blockIdx.x;   // 0..7 -> 256 d each
    const int b     = blockIdx.y;   // 0..127
    const int tid   = threadIdx.x;
    const int lane  = tid & 63;
    const int wv    = tid >> 6;

    __shared__ float wsm[NR];
    __shared__ float red[4];
    __shared__ float part2[4][32][8];

    float s = scores[b * NR + tid];
    float mx = s;
    #pragma unroll
    for (int d = 1; d < 64; d <<= 1) mx = fmaxf(mx, __shfl_xor(mx, d));
    if (lane == 0) red[wv] = mx;
    __syncthreads();
    mx = fmaxf(fmaxf(red[0], red[1]), fmaxf(red[2], red[3]));
    float e = __expf(s - mx);
    float sum = e;
    #pragma unroll
    for (int d = 1; d < 64; d <<= 1) sum += __shfl_xor(sum, d);
    __syncthreads();
    if (lane == 0) red[wv] = sum;
    __syncthreads();
    sum = red[0] + red[1] + red[2] + red[3];
    float w = e * (1.f / sum);
    wsm[tid] = w;
    if (chunk == 0) out[(size_t)NB * VIS_DIM + b * NR + tid] = w;
    __syncthreads();

    const int half  = lane >> 5;         // row parity
    const int dslot = lane & 31;         // 8-d slice id
    const int d0    = chunk * 256 + dslot * 8;
    const int kt    = d0 >> 6;           // image tile column
    const int ksl   = (d0 >> 3) & 7;     // 16B slot within a row
    const int rbase = b * 256 + wv * 64 + half;

    float acc[8] = {};
    #pragma unroll 4
    for (int step = 0; step < 32; ++step) {
        int rowg = rbase + step * 2;
        const char* p = (const char*)w16
            + ((size_t)(rowg >> 7) * 32 + kt) * TILE_B
            + (rowg & 127) * 128 + ((ksl ^ (rowg & 7)) << 4);
        short8 v = *(const short8*)p;
        float w_ = wsm[wv * 64 + step * 2 + half];
        #pragma unroll
        for (int j = 0; j < 8; ++j)
            acc[j] += w_ * bf2f((unsigned short)v[j]);
    }
    #pragma unroll
    for (int j = 0; j < 8; ++j) acc[j] += __shfl_xor(acc[j], 32);

    if (half == 0) {
        #pragma unroll
        for (int j = 0; j < 8; ++j) part2[wv][dslot][j] = acc[j];
    }
    __syncthreads();
    if (wv == 0 && half == 0) {
        float o[8];
        #pragma unroll
        for (int j = 0; j < 8; ++j)
            o[j] = part2[0][dslot][j] + part2[1][dslot][j]
                 + part2[2][dslot][j] + part2[3][dslot][j];
        float* dst = out + (size_t)b * VIS_DIM + chunk * 256 + dslot * 8;
        f32x4 lo = {o[0], o[1], o[2], o[3]};
        f32x4 hi = {o[4], o[5], o[6], o[7]};
        *(f32x4*)dst = lo;
        *(f32x4*)(dst + 4) = hi;
    }
}

// ---------------------------------------------------------------------------
// FALLBACK GEMM (R10 verbatim): used only when ws_size < WS_NEED.
// ---------------------------------------------------------------------------
#define BK 32
#define NT (VIS_DIM / BK)    // 64

static __device__ __forceinline__ int tile_off(int row, int kElem) {
    return row * 64 + (((kElem >> 3) ^ ((row >> 1) & 3)) << 4);
}

__global__ __launch_bounds__(256, 2) void gemm_vis(
        const float* __restrict__ A,
        const float* __restrict__ Bv,
        const float* __restrict__ bv,
        const float* __restrict__ wa,
        const float* __restrict__ tbuf,
        float* __restrict__ scores) {
    __shared__ __align__(16) char lds[32768];

    const int wg   = blockIdx.x;
    const int xcd  = wg & 7;
    const int loc  = wg >> 3;
    const int mb   = xcd * 32 + (loc >> 3);
    const int nb   = loc & 7;
    const int brow = mb * 128;
    const int bcol = nb * 128;

    const int tid  = threadIdx.x;
    const int lane = tid & 63;
    const int wid  = tid >> 6;
    const int wr   = wid >> 1, wc = wid & 1;

    const int srow = tid >> 3;
    const int sfs  = tid & 7;
    unsigned va0 = ((unsigned)(brow + srow      ) * VIS_DIM + sfs * 4) * 4u;
    unsigned va1 = va0 + 32u * VIS_DIM * 4u;
    unsigned va2 = va0 + 64u * VIS_DIM * 4u;
    unsigned va3 = va0 + 96u * VIS_DIM * 4u;
    unsigned vb0 = ((unsigned)(bcol + srow      ) * VIS_DIM + sfs * 4) * 4u;
    unsigned vb1 = vb0 + 32u * VIS_DIM * 4u;
    unsigned vb2 = vb0 + 64u * VIS_DIM * 4u;
    unsigned vb3 = vb0 + 96u * VIS_DIM * 4u;

    int wbyte[4];
    #pragma unroll
    for (int r = 0; r < 4; ++r) {
        int row = srow + 32 * r;
        wbyte[r] = row * 64 + (((sfs >> 1) ^ ((row >> 1) & 3)) << 4) + (sfs & 1) * 8;
    }

    f32x4 sA0, sA1, sA2, sA3, sB0, sB1, sB2, sB3;
    f32x4 tA0, tA1, tA2, tA3, tB0, tB1, tB2, tB3;
    f32x4 acc[4][4] = {};

#define GLOAD_SET(dA0,dA1,dA2,dA3,dB0,dB1,dB2,dB3)                             \
    do {                                                                       \
        asm volatile("global_load_dwordx4 %0, %1, %2"                          \
                     : "=&v"(dA0) : "v"(va0), "s"(A) : "memory");              \
        asm volatile("global_load_dwordx4 %0, %1, %2"                          \
                     : "=&v"(dA1) : "v"(va1), "s"(A) : "memory");              \
        asm volatile("global_load_dwordx4 %0, %1, %2"                          \
                     : "=&v"(dA2) : "v"(va2), "s"(A) : "memory");              \
        asm volatile("global_load_dwordx4 %0, %1, %2"                          \
                     : "=&v"(dA3) : "v"(va3), "s"(A) : "memory");              \
        asm volatile("global_load_dwordx4 %0, %1, %2"                          \
                     : "=&v"(dB0) : "v"(vb0), "s"(Bv) : "memory");             \
        asm volatile("global_load_dwordx4 %0, %1, %2"                          \
                     : "=&v"(dB1) : "v"(vb1), "s"(Bv) : "memory");             \
        asm volatile("global_load_dwordx4 %0, %1, %2"                          \
                     : "=&v"(dB2) : "v"(vb2), "s"(Bv) : "memory");             \
        asm volatile("global_load_dwordx4 %0, %1, %2"                          \
                     : "=&v"(dB3) : "v"(vb3), "s"(Bv) : "memory");             \
        va0 += BK * 4; va1 += BK * 4; va2 += BK * 4; va3 += BK * 4;            \
        vb0 += BK * 4; vb1 += BK * 4; vb2 += BK * 4; vb3 += BK * 4;            \
    } while (0)

#define GLOAD_S() GLOAD_SET(sA0,sA1,sA2,sA3,sB0,sB1,sB2,sB3)
#define GLOAD_T() GLOAD_SET(tA0,tA1,tA2,tA3,tB0,tB1,tB2,tB3)

#define VWAIT(N)                                                               \
    do {                                                                       \
        __builtin_amdgcn_sched_barrier(0);                                     \
        asm volatile("s_waitcnt vmcnt(" #N ")" ::: "memory");                  \
        __builtin_amdgcn_sched_barrier(0);                                     \
    } while (0)

#define BARRIER()                                                              \
    do {                                                                       \
        __builtin_amdgcn_sched_barrier(0);                                     \
        asm volatile("s_waitcnt lgkmcnt(0)" ::: "memory");                     \
        __builtin_amdgcn_s_barrier();                                          \
        __builtin_amdgcn_sched_barrier(0);                                     \
    } while (0)

#define CVT8(dst, v0)                                                          \
    do {                                                                       \
        u16x4 t_;                                                              \
        t_.x = f2bf((v0).x); t_.y = f2bf((v0).y);                              \
        t_.z = f2bf((v0).z); t_.w = f2bf((v0).w);                              \
        dst = t_;                                                              \
    } while (0)

#define LWRITE_SET(bufbase, dA0,dA1,dA2,dA3,dB0,dB1,dB2,dB3)                   \
    do {                                                                       \
        u16x4 w_;                                                              \
        char* la = lds + (bufbase);                                            \
        char* lb = lds + (bufbase) + 8192;                                     \
        CVT8(w_, dA0); *(u16x4*)(la + wbyte[0]) = w_;                          \
        CVT8(w_, dA1); *(u16x4*)(la + wbyte[1]) = w_;                          \
        CVT8(w_, dA2); *(u16x4*)(la + wbyte[2]) = w_;                          \
        CVT8(w_, dA3); *(u16x4*)(la + wbyte[3]) = w_;                          \
        CVT8(w_, dB0); *(u16x4*)(lb + wbyte[0]) = w_;                          \
        CVT8(w_, dB1); *(u16x4*)(lb + wbyte[1]) = w_;                          \
        CVT8(w_, dB2); *(u16x4*)(lb + wbyte[2]) = w_;                          \
        CVT8(w_, dB3); *(u16x4*)(lb + wbyte[3]) = w_;                          \
    } while (0)

#define LWRITE_S(bufbase) LWRITE_SET(bufbase, sA0,sA1,sA2,sA3,sB0,sB1,sB2,sB3)
#define LWRITE_T(bufbase) LWRITE_SET(bufbase, tA0,tA1,tA2,tA3,tB0,tB1,tB2,tB3)

#define COMPUTE(bufbase)                                                       \
    do {                                                                       \
        short8 af[4], bf[4];                                                   \
        const int kk = (lane >> 4) * 8;                                        \
        const char* la = lds + (bufbase);                                      \
        const char* lb = lds + (bufbase) + 8192;                               \
        _Pragma("unroll")                                                      \
        for (int m = 0; m < 4; ++m)                                            \
            af[m] = *(const short8*)(la + tile_off(wr*64 + m*16 + (lane&15), kk)); \
        _Pragma("unroll")                                                      \
        for (int n = 0; n < 4; ++n)                                            \
            bf[n] = *(const short8*)(lb + tile_off(wc*64 + n*16 + (lane&15), kk)); \
        _Pragma("unroll")                                                      \
        for (int m = 0; m < 4; ++m)                                            \
            _Pragma("unroll")                                                  \
            for (int n = 0; n < 4; ++n)                                        \
                acc[m][n] = __builtin_amdgcn_mfma_f32_16x16x32_bf16(           \
                    af[m], bf[n], acc[m][n], 0, 0, 0);                         \
    } while (0)

    GLOAD_S();
    GLOAD_T();
    VWAIT(8);
    LWRITE_S(0);
    BARRIER();

    #pragma unroll 1
    for (int kt = 0; kt < NT - 2; kt += 2) {
        GLOAD_S();
        COMPUTE(0);
        VWAIT(8);
        LWRITE_T(16384);
        BARRIER();
        GLOAD_T();
        COMPUTE(16384);
        VWAIT(8);
        LWRITE_S(0);
        BARRIER();
    }
    COMPUTE(0);
    VWAIT(0);
    LWRITE_T(16384);
    BARRIER();
    COMPUTE(16384);
#undef GLOAD_SET
#undef GLOAD_S
#undef GLOAD_T
#undef VWAIT
#undef BARRIER
#undef CVT8
#undef LWRITE_SET
#undef LWRITE_S
#undef LWRITE_T
#undef COMPUTE

    const int b = brow >> 8;
    float wa_c[4], bvt_c[4];
    #pragma unroll
    for (int n = 0; n < 4; ++n) {
        int col = bcol + wc * 64 + n * 16 + (lane & 15);
        wa_c[n]  = wa[col];
        bvt_c[n] = bv[col] + tbuf[b * HID + col];
    }
    #pragma unroll
    for (int m = 0; m < 4; ++m) {
        float p0 = 0.f, p1 = 0.f, p2 = 0.f, p3 = 0.f;
        #pragma unroll
        for (int n = 0; n < 4; ++n) {
            f32x4 v = acc[m][n];
            p0 += wa_c[n] * tanh_fast(v.x + bvt_c[n]);
            p1 += wa_c[n] * tanh_fast(v.y + bvt_c[n]);
            p2 += wa_c[n] * tanh_fast(v.z + bvt_c[n]);
            p3 += wa_c[n] * tanh_fast(v.w + bvt_c[n]);
        }
        #pragma unroll
        for (int d = 1; d < 16; d <<= 1) {
            p0 += __shfl_xor(p0, d); p1 += __shfl_xor(p1, d);
            p2 += __shfl_xor(p2, d); p3 += __shfl_xor(p3, d);
        }
        if ((lane & 15) == 0) {
            int rowg = brow + wr * 64 + m * 16 + (lane >> 4) * 4;
            atomicAdd(&scores[rowg + 0], p0);
            atomicAdd(&scores[rowg + 1], p1);
            atomicAdd(&scores[rowg + 2], p2);
            atomicAdd(&scores[rowg + 3], p3);
        }
    }
}

// ---------------------------------------------------------------------------
// fp32 attend (fallback path only)
// ---------------------------------------------------------------------------
__global__ __launch_bounds__(256) void attend(const float* __restrict__ visual,
                                              const float* __restrict__ scores,
                                              float* __restrict__ out) {
    const int chunk = blockIdx.x;
    const int b     = blockIdx.y;
    const int tid   = threadIdx.x;
    const int lane  = tid & 63;
    const int wv    = tid >> 6;

    __shared__ float wsm[NR];
    __shared__ float red[4];
    __shared__ f32x4 part[4][64];

    float s = scores[b * NR + tid];
    float mx = s;
    #pragma unroll
    for (int d = 1; d < 64; d <<= 1) mx = fmaxf(mx, __shfl_xor(mx, d));
    if (lane == 0) red[wv] = mx;
    __syncthreads();
    mx = fmaxf(fmaxf(red[0], red[1]), fmaxf(red[2], red[3]));
    float e = __expf(s - mx);
    float sum = e;
    #pragma unroll
    for (int d = 1; d < 64; d <<= 1) sum += __shfl_xor(sum, d);
    __syncthreads();
    if (lane == 0) red[wv] = sum;
    __syncthreads();
    sum = red[0] + red[1] + red[2] + red[3];
    float w = e * (1.f / sum);
    wsm[tid] = w;
    if (chunk == 0) out[(size_t)NB * VIS_DIM + b * NR + tid] = w;
    __syncthreads();

    const float* vb = visual + ((size_t)b * NR + wv * 64) * VIS_DIM + chunk * 256 + lane * 4;
    f32x4 acc = {0.f, 0.f, 0.f, 0.f};
    #pragma unroll
    for (int r = 0; r < 64; r += 4) {
        f32x4 v0 = *(const f32x4*)(vb + (size_t)(r + 0) * VIS_DIM);
        f32x4 v1 = *(const f32x4*)(vb + (size_t)(r + 1) * VIS_DIM);
        f32x4 v2 = *(const f32x4*)(vb + (size_t)(r + 2) * VIS_DIM);
        f32x4 v3 = *(const f32x4*)(vb + (size_t)(r + 3) * VIS_DIM);
        acc += wsm[wv * 64 + r + 0] * v0;
        acc += wsm[wv * 64 + r + 1] * v1;
        acc += wsm[wv * 64 + r + 2] * v2;
        acc += wsm[wv * 64 + r + 3] * v3;
    }
    part[wv][lane] = acc;
    __syncthreads();
    if (wv == 0) {
        f32x4 a = part[0][lane] + part[1][lane] + part[2][lane] + part[3][lane];
        *(f32x4*)(out + (size_t)b * VIS_DIM + chunk * 256 + lane * 4) = a;
    }
}

// ---------------------------------------------------------------------------
extern "C" void kernel_launch(void* const* d_in, const int* in_sizes, int n_in,
                              void* d_out, int out_size, void* d_ws, size_t ws_size,
                              hipStream_t stream) {
    (void)in_sizes; (void)n_in; (void)out_size;
    const float* visual = (const float*)d_in[0];
    const float* text   = (const float*)d_in[1];
    const float* Wv     = (const float*)d_in[2];
    const float* bv     = (const float*)d_in[3];
    const float* Wt     = (const float*)d_in[4];
    const float* bt     = (const float*)d_in[5];
    const float* Wa     = (const float*)d_in[6];
    // d_in[7] = ba : softmax-shift-invariant, unused.

    float* out = (float*)d_out;
    const bool fast = ws_size >= (size_t)WS_NEED;

    if (fast) {
        unsigned short* w16 = (unsigned short*)d_ws;
        float* scores = (float*)((char*)d_ws + WS_SCORES_OFF);
        float* tbuf   = scores + M_TOT;
        prepass    <<<N_TILES, 256, 0, stream>>>(visual, Wv, w16, scores, tbuf, bt);
        gemm_text  <<<dim3(32, 4), 256, 0, stream>>>(text, Wt, tbuf);
        gemm_256   <<<512, 256, 0, stream>>>(w16, bv, Wa, tbuf, scores);
        attend_bf16<<<dim3(8, NB), 256, 0, stream>>>(w16, scores, out);
    } else {
        float* scores = (float*)d_ws;
        float* tbuf   = scores + M_TOT;
        init_ws  <<<512, 256, 0, stream>>>(scores, tbuf, bt);
        gemm_text<<<dim3(32, 4), 256, 0, stream>>>(text, Wt, tbuf);
        gemm_vis <<<2048, 256, 0, stream>>>(visual, Wv, bv, Wa, tbuf, scores);
        attend   <<<dim3(8, NB), 256, 0, stream>>>(visual, scores, out);
    }
}

// Round 18
// 245.424 us; speedup vs baseline: 1.2824x; 1.2824x over previous
//
#include <hip/hip_runtime.h>
#include <hip/hip_bf16.h>

#define VIS_DIM 2048
#define TXT_DIM 1024
#define HID     1024
#define NB      128          // batch
#define NR      256          // regions
#define M_TOT   (NB*NR)      // 32768

// bf16 workspace layout (fast path):
//   A tiles: 8192 tiles (rowblk 0..255 x kt 0..31), 16KB each, swizzled image
//   B tiles: 256 tiles (colblk 0..7 x kt 0..31) at tile index 8192
//   scores (128KB) + tbuf (512KB) after the tiles
#define N_ATILES 8192
#define N_TILES  8448
#define TILE_B   16384
#define TSTRIDE  (32 * TILE_B)                              // +1 row-tile
#define WS_SCORES_OFF ((size_t)N_TILES * TILE_B)            // 138412032
#define WS_NEED (WS_SCORES_OFF + 131072 + 524288)           // 139067392

typedef __attribute__((ext_vector_type(4))) float  f32x4;
typedef __attribute__((ext_vector_type(8))) short  short8;   // 8 x bf16
typedef __attribute__((ext_vector_type(4))) unsigned short u16x4;

static __device__ __forceinline__ unsigned short f2bf(float f) {
    union { __hip_bfloat16 h; unsigned short u; } c;
    c.h = __float2bfloat16(f);
    return c.u;
}

static __device__ __forceinline__ float bf2f(unsigned short u) {
    union { float f; unsigned u; } c; c.u = ((unsigned)u) << 16; return c.f;
}

static __device__ __forceinline__ float tanh_fast(float x) {
    float xc = fminf(fmaxf(x, -15.f), 15.f);
    float e  = __expf(2.f * xc);
    return (e - 1.f) / (e + 1.f);
}

// ---------------------------------------------------------------------------
// prepass: fp32 -> bf16 tile-blocked, bank-swizzle baked into the layout.
// Tile (128 rows x 64 k) = 16KB; byte(row,k) = row*128 + (((k>>3)^(row&7))<<4)
// + (k&7)*2. Blocks 0..511 also do init (zero scores, tbuf = bt broadcast).
// ---------------------------------------------------------------------------
__global__ __launch_bounds__(256) void prepass(const float* __restrict__ A,
                                               const float* __restrict__ Bv,
                                               unsigned short* __restrict__ w16,
                                               float* __restrict__ scores,
                                               float* __restrict__ tbuf,
                                               const float* __restrict__ bt) {
    const int t   = blockIdx.x;
    const int tid = threadIdx.x;
    if (t < 512) {                       // fused init_ws (131072 elements)
        int i = t * 256 + tid;
        if (i < M_TOT) scores[i] = 0.f;
        tbuf[i] = bt[i & (HID - 1)];
    }
    const int mb  = (t < N_ATILES ? t : t - N_ATILES) >> 5;
    const int kt  = t & 31;
    const float* src = (t < N_ATILES ? A : Bv) + (size_t)mb * 128 * VIS_DIM + kt * 64;
    unsigned short* dst = w16 + (size_t)t * (TILE_B / 2);
    #pragma unroll
    for (int i = 0; i < 4; ++i) {
        int si = i * 256 + tid;          // 0..1023
        int row = si >> 3, slot = si & 7;
        const float* p = src + (size_t)row * VIS_DIM + slot * 8;
        f32x4 lo = *(const f32x4*)p;
        f32x4 hi = *(const f32x4*)(p + 4);
        short8 v;
        v[0] = (short)f2bf(lo.x); v[1] = (short)f2bf(lo.y);
        v[2] = (short)f2bf(lo.z); v[3] = (short)f2bf(lo.w);
        v[4] = (short)f2bf(hi.x); v[5] = (short)f2bf(hi.y);
        v[6] = (short)f2bf(hi.z); v[7] = (short)f2bf(hi.w);
        *(short8*)(dst + row * 64 + ((slot ^ (row & 7)) << 3)) = v;
    }
}

// ---------------------------------------------------------------------------
// init (fallback path only): zero scores, t = bt broadcast
// ---------------------------------------------------------------------------
__global__ void init_ws(float* __restrict__ scores, float* __restrict__ tbuf,
                        const float* __restrict__ bt) {
    int i = blockIdx.x * 256 + threadIdx.x;
    if (i < M_TOT) scores[i] = 0.f;
    tbuf[i] = bt[i & (HID - 1)];
}

// ---------------------------------------------------------------------------
// t = text @ Wt^T (+bt already in tbuf). Split-K fp32 tiled GEMM, atomicAdd.
// ---------------------------------------------------------------------------
__global__ __launch_bounds__(256) void gemm_text(const float* __restrict__ text,
                                                 const float* __restrict__ Wt,
                                                 float* __restrict__ tbuf) {
    __shared__ float As[128][33];
    __shared__ float Bs[32][33];
    const int n0  = blockIdx.x * 32;
    const int k0  = blockIdx.y * 256;
    const int tid = threadIdx.x;
    const int tm  = tid >> 3;
    const int tn  = tid & 7;
    float acc[4][4] = {};
    for (int kt = 0; kt < 8; ++kt) {
        const int k = k0 + kt * 32;
        {   // stage A: 128x32
            int row = tid >> 1, off = (tid & 1) * 16;
            const float* src = text + row * TXT_DIM + k + off;
            #pragma unroll
            for (int j = 0; j < 4; ++j) {
                f32x4 v = *(const f32x4*)(src + j * 4);
                As[row][off + j*4 + 0] = v.x; As[row][off + j*4 + 1] = v.y;
                As[row][off + j*4 + 2] = v.z; As[row][off + j*4 + 3] = v.w;
            }
        }
        {   // stage B: 32x32
            int row = tid >> 3, off = (tid & 7) * 4;
            f32x4 v = *(const f32x4*)(Wt + (size_t)(n0 + row) * TXT_DIM + k + off);
            Bs[row][off + 0] = v.x; Bs[row][off + 1] = v.y;
            Bs[row][off + 2] = v.z; Bs[row][off + 3] = v.w;
        }
        __syncthreads();
        #pragma unroll
        for (int kk = 0; kk < 32; ++kk) {
            float a[4], b[4];
            #pragma unroll
            for (int i = 0; i < 4; ++i) a[i] = As[tm*4 + i][kk];
            #pragma unroll
            for (int j = 0; j < 4; ++j) b[j] = Bs[tn*4 + j][kk];
            #pragma unroll
            for (int i = 0; i < 4; ++i)
                #pragma unroll
                for (int j = 0; j < 4; ++j) acc[i][j] += a[i] * b[j];
        }
        __syncthreads();
    }
    #pragma unroll
    for (int i = 0; i < 4; ++i)
        #pragma unroll
        for (int j = 0; j < 4; ++j)
            atomicAdd(&tbuf[(tm*4 + i) * HID + n0 + tn*4 + j], acc[i][j]);
}

// ---------------------------------------------------------------------------
// gemm_256 (R16 verbatim -- measured best ~118us): 256x256 tile, BK=64,
// 8 waves (wave tile 128x64, acc[8][4]), 2-phase K-tile, reg-first fragment
// loads then setprio'd 32-MFMA cluster, double-buffered 128KB LDS, raw
// barriers, counted prefetch (tile t+1 issued one full tile early).
// R17's 128x128 wave tile (acc[8][8]=256 VGPR) hit the 256-reg allocation
// cap and spilled (WRITE 20MB, 212us). R15's 4-phase regressed (8 barriers/
// tile at 1 block/CU stalls the whole CU). This 2-phase shape is the
// optimum of the explored space.
// ---------------------------------------------------------------------------
static __device__ __forceinline__ int toff(int row, int kElem) {
    return row * 128 + ((((kElem >> 3) & 7) ^ (row & 7)) << 4);
}

__global__ __launch_bounds__(512, 2) void gemm_256(
        const unsigned short* __restrict__ w16,
        const float* __restrict__ bv,
        const float* __restrict__ wa,
        const float* __restrict__ tbuf,
        float* __restrict__ scores) {
    // per buffer (64KB): A0,A1,B0,B1 tiles at 0,16K,32K,48K; buf1 at +64K
    __shared__ __align__(16) char lds[131072];

    // 512 blocks = 128 mb x 4 nb; XCD-chunked: each XCD owns 16 mb-groups,
    // nb-fastest so the 4 column-siblings of an A-panel are adjacent.
    const int wg   = blockIdx.x;
    const int xcd  = wg & 7;
    const int loc  = wg >> 3;               // 0..63
    const int mb   = xcd * 16 + (loc >> 2); // 0..127
    const int nb   = loc & 3;               // 0..3
    const int brow = mb * 256;
    const int bcol = nb * 256;

    const int tid  = threadIdx.x;           // 512 thr, 8 waves
    const int lane = tid & 63;
    const int wid  = tid >> 6;              // 0..7
    const int wr   = wid >> 2;              // 0..1 (row half: 128 rows)
    const int wc   = wid & 3;               // 0..3 (col quarter: 64 cols)
    const int l    = lane & 15, g = lane >> 4;

    // staging source pointers (per-lane global addresses)
    const char* wb = (const char*)w16;
    const char* pA = wb + (size_t)(2 * mb) * TSTRIDE + wid * 1024 + lane * 16;
    const char* pB = wb + (size_t)N_ATILES * TILE_B
                        + (size_t)(2 * nb) * TSTRIDE + wid * 1024 + lane * 16;

    f32x4 acc[8][4] = {};

    // issue 8 global_load_lds (8KB each, block-wide) for K-tile at byte koff
#define GLOADS(koff, bufbase)                                                  \
    do {                                                                       \
        _Pragma("unroll")                                                      \
        for (int j = 0; j < 8; ++j) {                                          \
            const char* s_ = (j < 4                                            \
                ? pA + (j >> 1) * (size_t)TSTRIDE + (j & 1) * 8192             \
                : pB + ((j - 4) >> 1) * (size_t)TSTRIDE + ((j - 4) & 1) * 8192)\
                + (koff);                                                      \
            __builtin_amdgcn_global_load_lds(                                  \
                (const __attribute__((address_space(1))) float*)s_,            \
                (__attribute__((address_space(3))) float*)                     \
                    (lds + (bufbase) + j * 8192 + wid * 1024),                 \
                16, 0, 0);                                                     \
        }                                                                      \
    } while (0)

#define VWAIT0()                                                               \
    do {                                                                       \
        __builtin_amdgcn_sched_barrier(0);                                     \
        asm volatile("s_waitcnt vmcnt(0)" ::: "memory");                       \
        __builtin_amdgcn_sched_barrier(0);                                     \
    } while (0)

#define BARRIER()                                                              \
    do {                                                                       \
        __builtin_amdgcn_sched_barrier(0);                                     \
        asm volatile("s_waitcnt lgkmcnt(0)" ::: "memory");                     \
        __builtin_amdgcn_s_barrier();                                          \
        __builtin_amdgcn_sched_barrier(0);                                     \
    } while (0)

    // one k-slice (32): load 12 frags to regs, then setprio'd 32-MFMA cluster
#define PHASE(bufbase, s)                                                      \
    do {                                                                       \
        const int kE = (s) * 32 + g * 8;                                       \
        const char* pa_ = lds + (bufbase) + wr * 16384;                        \
        const char* pb_ = lds + (bufbase) + 32768 + (wc >> 1) * 16384;         \
        short8 bfr[4], afr[8];                                                 \
        _Pragma("unroll")                                                      \
        for (int n = 0; n < 4; ++n)                                            \
            bfr[n] = *(const short8*)(pb_ + toff((wc & 1) * 64 + n * 16 + l, kE)); \
        _Pragma("unroll")                                                      \
        for (int m = 0; m < 8; ++m)                                            \
            afr[m] = *(const short8*)(pa_ + toff(m * 16 + l, kE));             \
        __builtin_amdgcn_s_setprio(1);                                         \
        _Pragma("unroll")                                                      \
        for (int m = 0; m < 8; ++m) {                                          \
            acc[m][0] = __builtin_amdgcn_mfma_f32_16x16x32_bf16(afr[m], bfr[0], acc[m][0], 0, 0, 0); \
            acc[m][1] = __builtin_amdgcn_mfma_f32_16x16x32_bf16(afr[m], bfr[1], acc[m][1], 0, 0, 0); \
            acc[m][2] = __builtin_amdgcn_mfma_f32_16x16x32_bf16(afr[m], bfr[2], acc[m][2], 0, 0, 0); \
            acc[m][3] = __builtin_amdgcn_mfma_f32_16x16x32_bf16(afr[m], bfr[3], acc[m][3], 0, 0, 0); \
        }                                                                      \
        __builtin_amdgcn_s_setprio(0);                                         \
    } while (0)

    // Prologue: tile0 -> buf0 (drained), tile1 -> buf1 (in flight)
    GLOADS((size_t)0, 0);
    VWAIT0();
    GLOADS((size_t)TILE_B, 65536);
    BARRIER();                 // tile0 visible; tile1 flying

    // 16 pair-iterations over 32 K-tiles. Invariant at iter top: buf0 holds
    // tile 2i (synced); tile 2i+1's loads in flight into buf1.
    #pragma unroll 1
    for (int i = 0; i < 16; ++i) {
        const size_t k2 = (size_t)(2 * i + 2) * TILE_B;
        PHASE(0, 0);
        PHASE(0, 1);           // tile 2i computed
        VWAIT0();              // tile 2i+1 landed (hidden under compute)
        BARRIER();             // everyone done reading buf0
        if (i < 15) GLOADS(k2, 0);            // tile 2i+2 -> buf0 (flying)
        PHASE(65536, 0);
        PHASE(65536, 1);       // tile 2i+1 computed
        if (i < 15) {
            VWAIT0();          // tile 2i+2 landed
            BARRIER();         // everyone done reading buf1
            GLOADS(k2 + TILE_B, 65536);       // tile 2i+3 -> buf1 (flying)
        }
    }
#undef GLOADS
#undef VWAIT0
#undef BARRIER
#undef PHASE

    // ---- epilogue: tanh + Wa-dot, reduce over 16 cols/lane-group, atomicAdd
    const int b = mb;                        // block == one batch (256 rows)
    float wa_c[4], bvt_c[4];
    #pragma unroll
    for (int n = 0; n < 4; ++n) {
        int col = bcol + wc * 64 + n * 16 + l;
        wa_c[n]  = wa[col];
        bvt_c[n] = bv[col] + tbuf[b * HID + col];
    }
    #pragma unroll
    for (int m = 0; m < 8; ++m) {
        float p0 = 0.f, p1 = 0.f, p2 = 0.f, p3 = 0.f;
        #pragma unroll
        for (int n = 0; n < 4; ++n) {
            f32x4 v = acc[m][n];
            p0 += wa_c[n] * tanh_fast(v.x + bvt_c[n]);
            p1 += wa_c[n] * tanh_fast(v.y + bvt_c[n]);
            p2 += wa_c[n] * tanh_fast(v.z + bvt_c[n]);
            p3 += wa_c[n] * tanh_fast(v.w + bvt_c[n]);
        }
        #pragma unroll
        for (int d = 1; d < 16; d <<= 1) {
            p0 += __shfl_xor(p0, d); p1 += __shfl_xor(p1, d);
            p2 += __shfl_xor(p2, d); p3 += __shfl_xor(p3, d);
        }
        if ((lane & 15) == 0) {
            int rowg = brow + wr * 128 + m * 16 + g * 4;
            atomicAdd(&scores[rowg + 0], p0);
            atomicAdd(&scores[rowg + 1], p1);
            atomicAdd(&scores[rowg + 2], p2);
            atomicAdd(&scores[rowg + 3], p3);
        }
    }
}

// ---------------------------------------------------------------------------
// attend_bf16: softmax + attended = w . visual, reading the bf16 tile image
// (128 MB, mostly L3-resident after gemm_256) instead of fp32 visual.
// ---------------------------------------------------------------------------
__global__ __launch_bounds__(256) void attend_bf16(
        const unsigned short* __restrict__ w16,
        const float* __restrict__ scores,
        float* __restrict__ out) {
    const int chunk = blockIdx.x;   // 0..7 -> 256 d each
    const int b     = blockIdx.y;   // 0..127
    const int tid   = threadIdx.x;
    const int lane  = tid & 63;
    const int wv    = tid >> 6;

    __shared__ float wsm[NR];
    __shared__ float red[4];
    __shared__ float part2[4][32][8];

    float s = scores[b * NR + tid];
    float mx = s;
    #pragma unroll
    for (int d = 1; d < 64; d <<= 1) mx = fmaxf(mx, __shfl_xor(mx, d));
    if (lane == 0) red[wv] = mx;
    __syncthreads();
    mx = fmaxf(fmaxf(red[0], red[1]), fmaxf(red[2], red[3]));
    float e = __expf(s - mx);
    float sum = e;
    #pragma unroll
    for (int d = 1; d < 64; d <<= 1) sum += __shfl_xor(sum, d);
    __syncthreads();
    if (lane == 0) red[wv] = sum;
    __syncthreads();
    sum = red[0] + red[1] + red[2] + red[3];
    float w = e * (1.f / sum);
    wsm[tid] = w;
    if (chunk == 0) out[(size_t)NB * VIS_DIM + b * NR + tid] = w;
    __syncthreads();

    const int half  = lane >> 5;         // row parity
    const int dslot = lane & 31;         // 8-d slice id
    const int d0    = chunk * 256 + dslot * 8;
    const int kt    = d0 >> 6;           // image tile column
    const int ksl   = (d0 >> 3) & 7;     // 16B slot within a row
    const int rbase = b * 256 + wv * 64 + half;

    float acc[8] = {};
    #pragma unroll 4
    for (int step = 0; step < 32; ++step) {
        int rowg = rbase + step * 2;
        const char* p = (const char*)w16
            + ((size_t)(rowg >> 7) * 32 + kt) * TILE_B
            + (rowg & 127) * 128 + ((ksl ^ (rowg & 7)) << 4);
        short8 v = *(const short8*)p;
        float w_ = wsm[wv * 64 + step * 2 + half];
        #pragma unroll
        for (int j = 0; j < 8; ++j)
            acc[j] += w_ * bf2f((unsigned short)v[j]);
    }
    #pragma unroll
    for (int j = 0; j < 8; ++j) acc[j] += __shfl_xor(acc[j], 32);

    if (half == 0) {
        #pragma unroll
        for (int j = 0; j < 8; ++j) part2[wv][dslot][j] = acc[j];
    }
    __syncthreads();
    if (wv == 0 && half == 0) {
        float o[8];
        #pragma unroll
        for (int j = 0; j < 8; ++j)
            o[j] = part2[0][dslot][j] + part2[1][dslot][j]
                 + part2[2][dslot][j] + part2[3][dslot][j];
        float* dst = out + (size_t)b * VIS_DIM + chunk * 256 + dslot * 8;
        f32x4 lo = {o[0], o[1], o[2], o[3]};
        f32x4 hi = {o[4], o[5], o[6], o[7]};
        *(f32x4*)dst = lo;
        *(f32x4*)(dst + 4) = hi;
    }
}

// ---------------------------------------------------------------------------
// FALLBACK GEMM (R10 verbatim): used only when ws_size < WS_NEED.
// ---------------------------------------------------------------------------
#define BK 32
#define NT (VIS_DIM / BK)    // 64

static __device__ __forceinline__ int tile_off(int row, int kElem) {
    return row * 64 + (((kElem >> 3) ^ ((row >> 1) & 3)) << 4);
}

__global__ __launch_bounds__(256, 2) void gemm_vis(
        const float* __restrict__ A,
        const float* __restrict__ Bv,
        const float* __restrict__ bv,
        const float* __restrict__ wa,
        const float* __restrict__ tbuf,
        float* __restrict__ scores) {
    __shared__ __align__(16) char lds[32768];

    const int wg   = blockIdx.x;
    const int xcd  = wg & 7;
    const int loc  = wg >> 3;
    const int mb   = xcd * 32 + (loc >> 3);
    const int nb   = loc & 7;
    const int brow = mb * 128;
    const int bcol = nb * 128;

    const int tid  = threadIdx.x;
    const int lane = tid & 63;
    const int wid  = tid >> 6;
    const int wr   = wid >> 1, wc = wid & 1;

    const int srow = tid >> 3;
    const int sfs  = tid & 7;
    unsigned va0 = ((unsigned)(brow + srow      ) * VIS_DIM + sfs * 4) * 4u;
    unsigned va1 = va0 + 32u * VIS_DIM * 4u;
    unsigned va2 = va0 + 64u * VIS_DIM * 4u;
    unsigned va3 = va0 + 96u * VIS_DIM * 4u;
    unsigned vb0 = ((unsigned)(bcol + srow      ) * VIS_DIM + sfs * 4) * 4u;
    unsigned vb1 = vb0 + 32u * VIS_DIM * 4u;
    unsigned vb2 = vb0 + 64u * VIS_DIM * 4u;
    unsigned vb3 = vb0 + 96u * VIS_DIM * 4u;

    int wbyte[4];
    #pragma unroll
    for (int r = 0; r < 4; ++r) {
        int row = srow + 32 * r;
        wbyte[r] = row * 64 + (((sfs >> 1) ^ ((row >> 1) & 3)) << 4) + (sfs & 1) * 8;
    }

    f32x4 sA0, sA1, sA2, sA3, sB0, sB1, sB2, sB3;
    f32x4 tA0, tA1, tA2, tA3, tB0, tB1, tB2, tB3;
    f32x4 acc[4][4] = {};

#define GLOAD_SET(dA0,dA1,dA2,dA3,dB0,dB1,dB2,dB3)                             \
    do {                                                                       \
        asm volatile("global_load_dwordx4 %0, %1, %2"                          \
                     : "=&v"(dA0) : "v"(va0), "s"(A) : "memory");              \
        asm volatile("global_load_dwordx4 %0, %1, %2"                          \
                     : "=&v"(dA1) : "v"(va1), "s"(A) : "memory");              \
        asm volatile("global_load_dwordx4 %0, %1, %2"                          \
                     : "=&v"(dA2) : "v"(va2), "s"(A) : "memory");              \
        asm volatile("global_load_dwordx4 %0, %1, %2"                          \
                     : "=&v"(dA3) : "v"(va3), "s"(A) : "memory");              \
        asm volatile("global_load_dwordx4 %0, %1, %2"                          \
                     : "=&v"(dB0) : "v"(vb0), "s"(Bv) : "memory");             \
        asm volatile("global_load_dwordx4 %0, %1, %2"                          \
                     : "=&v"(dB1) : "v"(vb1), "s"(Bv) : "memory");             \
        asm volatile("global_load_dwordx4 %0, %1, %2"                          \
                     : "=&v"(dB2) : "v"(vb2), "s"(Bv) : "memory");             \
        asm volatile("global_load_dwordx4 %0, %1, %2"                          \
                     : "=&v"(dB3) : "v"(vb3), "s"(Bv) : "memory");             \
        va0 += BK * 4; va1 += BK * 4; va2 += BK * 4; va3 += BK * 4;            \
        vb0 += BK * 4; vb1 += BK * 4; vb2 += BK * 4; vb3 += BK * 4;            \
    } while (0)

#define GLOAD_S() GLOAD_SET(sA0,sA1,sA2,sA3,sB0,sB1,sB2,sB3)
#define GLOAD_T() GLOAD_SET(tA0,tA1,tA2,tA3,tB0,tB1,tB2,tB3)

#define VWAIT(N)                                                               \
    do {                                                                       \
        __builtin_amdgcn_sched_barrier(0);                                     \
        asm volatile("s_waitcnt vmcnt(" #N ")" ::: "memory");                  \
        __builtin_amdgcn_sched_barrier(0);                                     \
    } while (0)

#define BARRIER()                                                              \
    do {                                                                       \
        __builtin_amdgcn_sched_barrier(0);                                     \
        asm volatile("s_waitcnt lgkmcnt(0)" ::: "memory");                     \
        __builtin_amdgcn_s_barrier();                                          \
        __builtin_amdgcn_sched_barrier(0);                                     \
    } while (0)

#define CVT8(dst, v0)                                                          \
    do {                                                                       \
        u16x4 t_;                                                              \
        t_.x = f2bf((v0).x); t_.y = f2bf((v0).y);                              \
        t_.z = f2bf((v0).z); t_.w = f2bf((v0).w);                              \
        dst = t_;                                                              \
    } while (0)

#define LWRITE_SET(bufbase, dA0,dA1,dA2,dA3,dB0,dB1,dB2,dB3)                   \
    do {                                                                       \
        u16x4 w_;                                                              \
        char* la = lds + (bufbase);                                            \
        char* lb = lds + (bufbase) + 8192;                                     \
        CVT8(w_, dA0); *(u16x4*)(la + wbyte[0]) = w_;                          \
        CVT8(w_, dA1); *(u16x4*)(la + wbyte[1]) = w_;                          \
        CVT8(w_, dA2); *(u16x4*)(la + wbyte[2]) = w_;                          \
        CVT8(w_, dA3); *(u16x4*)(la + wbyte[3]) = w_;                          \
        CVT8(w_, dB0); *(u16x4*)(lb + wbyte[0]) = w_;                          \
        CVT8(w_, dB1); *(u16x4*)(lb + wbyte[1]) = w_;                          \
        CVT8(w_, dB2); *(u16x4*)(lb + wbyte[2]) = w_;                          \
        CVT8(w_, dB3); *(u16x4*)(lb + wbyte[3]) = w_;                          \
    } while (0)

#define LWRITE_S(bufbase) LWRITE_SET(bufbase, sA0,sA1,sA2,sA3,sB0,sB1,sB2,sB3)
#define LWRITE_T(bufbase) LWRITE_SET(bufbase, tA0,tA1,tA2,tA3,tB0,tB1,tB2,tB3)

#define COMPUTE(bufbase)                                                       \
    do {                                                                       \
        short8 af[4], bf[4];                                                   \
        const int kk = (lane >> 4) * 8;                                        \
        const char* la = lds + (bufbase);                                      \
        const char* lb = lds + (bufbase) + 8192;                               \
        _Pragma("unroll")                                                      \
        for (int m = 0; m < 4; ++m)                                            \
            af[m] = *(const short8*)(la + tile_off(wr*64 + m*16 + (lane&15), kk)); \
        _Pragma("unroll")                                                      \
        for (int n = 0; n < 4; ++n)                                            \
            bf[n] = *(const short8*)(lb + tile_off(wc*64 + n*16 + (lane&15), kk)); \
        _Pragma("unroll")                                                      \
        for (int m = 0; m < 4; ++m)                                            \
            _Pragma("unroll")                                                  \
            for (int n = 0; n < 4; ++n)                                        \
                acc[m][n] = __builtin_amdgcn_mfma_f32_16x16x32_bf16(           \
                    af[m], bf[n], acc[m][n], 0, 0, 0);                         \
    } while (0)

    GLOAD_S();
    GLOAD_T();
    VWAIT(8);
    LWRITE_S(0);
    BARRIER();

    #pragma unroll 1
    for (int kt = 0; kt < NT - 2; kt += 2) {
        GLOAD_S();
        COMPUTE(0);
        VWAIT(8);
        LWRITE_T(16384);
        BARRIER();
        GLOAD_T();
        COMPUTE(16384);
        VWAIT(8);
        LWRITE_S(0);
        BARRIER();
    }
    COMPUTE(0);
    VWAIT(0);
    LWRITE_T(16384);
    BARRIER();
    COMPUTE(16384);
#undef GLOAD_SET
#undef GLOAD_S
#undef GLOAD_T
#undef VWAIT
#undef BARRIER
#undef CVT8
#undef LWRITE_SET
#undef LWRITE_S
#undef LWRITE_T
#undef COMPUTE

    const int b = brow >> 8;
    float wa_c[4], bvt_c[4];
    #pragma unroll
    for (int n = 0; n < 4; ++n) {
        int col = bcol + wc * 64 + n * 16 + (lane & 15);
        wa_c[n]  = wa[col];
        bvt_c[n] = bv[col] + tbuf[b * HID + col];
    }
    #pragma unroll
    for (int m = 0; m < 4; ++m) {
        float p0 = 0.f, p1 = 0.f, p2 = 0.f, p3 = 0.f;
        #pragma unroll
        for (int n = 0; n < 4; ++n) {
            f32x4 v = acc[m][n];
            p0 += wa_c[n] * tanh_fast(v.x + bvt_c[n]);
            p1 += wa_c[n] * tanh_fast(v.y + bvt_c[n]);
            p2 += wa_c[n] * tanh_fast(v.z + bvt_c[n]);
            p3 += wa_c[n] * tanh_fast(v.w + bvt_c[n]);
        }
        #pragma unroll
        for (int d = 1; d < 16; d <<= 1) {
            p0 += __shfl_xor(p0, d); p1 += __shfl_xor(p1, d);
            p2 += __shfl_xor(p2, d); p3 += __shfl_xor(p3, d);
        }
        if ((lane & 15) == 0) {
            int rowg = brow + wr * 64 + m * 16 + (lane >> 4) * 4;
            atomicAdd(&scores[rowg + 0], p0);
            atomicAdd(&scores[rowg + 1], p1);
            atomicAdd(&scores[rowg + 2], p2);
            atomicAdd(&scores[rowg + 3], p3);
        }
    }
}

// ---------------------------------------------------------------------------
// fp32 attend (fallback path only)
// ---------------------------------------------------------------------------
__global__ __launch_bounds__(256) void attend(const float* __restrict__ visual,
                                              const float* __restrict__ scores,
                                              float* __restrict__ out) {
    const int chunk = blockIdx.x;
    const int b     = blockIdx.y;
    const int tid   = threadIdx.x;
    const int lane  = tid & 63;
    const int wv    = tid >> 6;

    __shared__ float wsm[NR];
    __shared__ float red[4];
    __shared__ f32x4 part[4][64];

    float s = scores[b * NR + tid];
    float mx = s;
    #pragma unroll
    for (int d = 1; d < 64; d <<= 1) mx = fmaxf(mx, __shfl_xor(mx, d));
    if (lane == 0) red[wv] = mx;
    __syncthreads();
    mx = fmaxf(fmaxf(red[0], red[1]), fmaxf(red[2], red[3]));
    float e = __expf(s - mx);
    float sum = e;
    #pragma unroll
    for (int d = 1; d < 64; d <<= 1) sum += __shfl_xor(sum, d);
    __syncthreads();
    if (lane == 0) red[wv] = sum;
    __syncthreads();
    sum = red[0] + red[1] + red[2] + red[3];
    float w = e * (1.f / sum);
    wsm[tid] = w;
    if (chunk == 0) out[(size_t)NB * VIS_DIM + b * NR + tid] = w;
    __syncthreads();

    const float* vb = visual + ((size_t)b * NR + wv * 64) * VIS_DIM + chunk * 256 + lane * 4;
    f32x4 acc = {0.f, 0.f, 0.f, 0.f};
    #pragma unroll
    for (int r = 0; r < 64; r += 4) {
        f32x4 v0 = *(const f32x4*)(vb + (size_t)(r + 0) * VIS_DIM);
        f32x4 v1 = *(const f32x4*)(vb + (size_t)(r + 1) * VIS_DIM);
        f32x4 v2 = *(const f32x4*)(vb + (size_t)(r + 2) * VIS_DIM);
        f32x4 v3 = *(const f32x4*)(vb + (size_t)(r + 3) * VIS_DIM);
        acc += wsm[wv * 64 + r + 0] * v0;
        acc += wsm[wv * 64 + r + 1] * v1;
        acc += wsm[wv * 64 + r + 2] * v2;
        acc += wsm[wv * 64 + r + 3] * v3;
    }
    part[wv][lane] = acc;
    __syncthreads();
    if (wv == 0) {
        f32x4 a = part[0][lane] + part[1][lane] + part[2][lane] + part[3][lane];
        *(f32x4*)(out + (size_t)b * VIS_DIM + chunk * 256 + lane * 4) = a;
    }
}

// ---------------------------------------------------------------------------
extern "C" void kernel_launch(void* const* d_in, const int* in_sizes, int n_in,
                              void* d_out, int out_size, void* d_ws, size_t ws_size,
                              hipStream_t stream) {
    (void)in_sizes; (void)n_in; (void)out_size;
    const float* visual = (const float*)d_in[0];
    const float* text   = (const float*)d_in[1];
    const float* Wv     = (const float*)d_in[2];
    const float* bv     = (const float*)d_in[3];
    const float* Wt     = (const float*)d_in[4];
    const float* bt     = (const float*)d_in[5];
    const float* Wa     = (const float*)d_in[6];
    // d_in[7] = ba : softmax-shift-invariant, unused.

    float* out = (float*)d_out;
    const bool fast = ws_size >= (size_t)WS_NEED;

    if (fast) {
        unsigned short* w16 = (unsigned short*)d_ws;
        float* scores = (float*)((char*)d_ws + WS_SCORES_OFF);
        float* tbuf   = scores + M_TOT;
        prepass    <<<N_TILES, 256, 0, stream>>>(visual, Wv, w16, scores, tbuf, bt);
        gemm_text  <<<dim3(32, 4), 256, 0, stream>>>(text, Wt, tbuf);
        gemm_256   <<<512, 512, 0, stream>>>(w16, bv, Wa, tbuf, scores);
        attend_bf16<<<dim3(8, NB), 256, 0, stream>>>(w16, scores, out);
    } else {
        float* scores = (float*)d_ws;
        float* tbuf   = scores + M_TOT;
        init_ws  <<<512, 256, 0, stream>>>(scores, tbuf, bt);
        gemm_text<<<dim3(32, 4), 256, 0, stream>>>(text, Wt, tbuf);
        gemm_vis <<<2048, 256, 0, stream>>>(visual, Wv, bv, Wa, tbuf, scores);
        attend   <<<dim3(8, NB), 256, 0, stream>>>(visual, scores, out);
    }
}